// Round 10
// baseline (826.461 us; speedup 1.0000x reference)
//
#include <hip/hip_runtime.h>
#include <hip/hip_bf16.h>

// B=16, N=1024, R=10, De=64, Dr=32, H=64, cat_in=960
// out[b,m,h] = relu( bias[h] + sum_r sum_n adj[b,r,m,n] * Yt[br,h,n] )
// Yt[br,h,n] = sum_d x[b,n,d]*W[h, r*96+d] + c[br,h]
// c[br,h]    = sum_d rel[br,d]*W[h, r*96+64+d]
//
// MEASUREMENT ROUND: layer-1 main = 128-block fused variant (~500 us) so it
// ranks in the profiler top-5 and finally yields counters for the adj stream.
// Layer 2 = exact r1-validated fast path.

typedef __bf16 bf16x8 __attribute__((ext_vector_type(8)));
typedef float  f32x4  __attribute__((ext_vector_type(4)));
typedef float  f32x8  __attribute__((ext_vector_type(8)));

// ---------------- prep kernel: c (fused) + Yt[br,h,n] (bf16, linear) ----------------
__global__ __launch_bounds__(256)
void rgcn_prep(const float* __restrict__ x, const float* __restrict__ rel,
               const float* __restrict__ W, __bf16* __restrict__ yt) {
    const int r = blockIdx.y, b = blockIdx.z;
    const int br = b * 10 + r;

    __shared__ float csh[64];
    if (threadIdx.x < 64) {
        const int h = threadIdx.x;
        const float* rp = rel + (size_t)br * 32;
        const float* wp = W + (size_t)h * 960 + r * 96 + 64;
        float a = 0.f;
#pragma unroll
        for (int d = 0; d < 32; ++d) a += rp[d] * wp[d];
        csh[h] = a;
    }
    __syncthreads();

    const int n = blockIdx.x * 256 + threadIdx.x;   // 0..1023
    float xr[64];
    const float* xp = x + ((size_t)b * 1024 + n) * 64;
#pragma unroll
    for (int j = 0; j < 16; ++j) {
        const float4 v = *(const float4*)(xp + j * 4);
        xr[j * 4 + 0] = v.x; xr[j * 4 + 1] = v.y;
        xr[j * 4 + 2] = v.z; xr[j * 4 + 3] = v.w;
    }

    const float* wbase = W + r * 96;                 // W[h*960 + r*96 + d]
    __bf16* yb = yt + ((size_t)br << 16) + n;        // Yt[br][h][n], linear
    for (int h = 0; h < 64; ++h) {                   // h,d wave-uniform -> W scalar loads
        float acc = csh[h];
        const float* wr = wbase + (size_t)h * 960;
#pragma unroll
        for (int d = 0; d < 64; ++d) acc += xr[d] * wr[d];
        yb[(size_t)h << 10] = (__bf16)acc;
    }
}

// ---------------- fused main (measurement target): 128 blocks, NR=10 ----------------
// grid (8 mtile, 1, 16 b), 256 thr = 4 waves, wave owns 32m x 64h; loops all 10
// relations, fused bias+relu, writes dst directly. Body = r1's validated FUSE path.
__global__ __launch_bounds__(256, 2)
void rgcn_mainF(const float* __restrict__ adj, const __bf16* __restrict__ yt,
                const float* __restrict__ bias, float* __restrict__ dst) {
    const int mtile = blockIdx.x, b = blockIdx.z;
    const int w = threadIdx.x >> 6, lane = threadIdx.x & 63;
    const int g = lane >> 4, lm = lane & 15;
    const int mbase = mtile * 128 + w * 32;

    f32x4 acc[2][4] = {};
    for (int r = 0; r < 10; ++r) {
        const int br = b * 10 + r;
        const float*  a0 = adj + (((size_t)br * 1024 + mbase + lm) << 10) + g * 8;
        const __bf16* y0 = yt  + (((size_t)br * 64 + lm) << 10) + g * 8;
        for (int n0 = 0; n0 < 1024; n0 += 32) {
            const f32x8 v0 = *(const f32x8*)(a0 + n0);
            const f32x8 v1 = *(const f32x8*)(a0 + (16 << 10) + n0);
            bf16x8 av0, av1;
#pragma unroll
            for (int j = 0; j < 8; ++j) { av0[j] = (__bf16)v0[j]; av1[j] = (__bf16)v1[j]; }
#pragma unroll
            for (int hf = 0; hf < 4; ++hf) {
                const bf16x8 bv = *(const bf16x8*)(y0 + hf * 16384 + n0);
                acc[0][hf] = __builtin_amdgcn_mfma_f32_16x16x32_bf16(av0, bv, acc[0][hf], 0, 0, 0);
                acc[1][hf] = __builtin_amdgcn_mfma_f32_16x16x32_bf16(av1, bv, acc[1][hf], 0, 0, 0);
            }
        }
    }
    float bvals[4];
#pragma unroll
    for (int hf = 0; hf < 4; ++hf) bvals[hf] = bias[hf * 16 + lm];
    float* db = dst + ((size_t)(b * 1024 + mbase)) * 64;
#pragma unroll
    for (int mf = 0; mf < 2; ++mf)
#pragma unroll
        for (int hf = 0; hf < 4; ++hf)
#pragma unroll
            for (int reg = 0; reg < 4; ++reg) {
                const int m = mf * 16 + g * 4 + reg;
                const int h = hf * 16 + lm;
                db[((size_t)m << 6) + h] = fmaxf(acc[mf][hf][reg] + bvals[hf], 0.f);
            }
}

// ---------------- fast main (layer 2): grid (8,5,16), NR=2, partial out ----------------
__global__ __launch_bounds__(256, 2)
void rgcn_main(const float* __restrict__ adj, const __bf16* __restrict__ yt,
               float* __restrict__ partial) {
    const int mtile = blockIdx.x, rg = blockIdx.y, b = blockIdx.z;
    const int w = threadIdx.x >> 6, lane = threadIdx.x & 63;
    const int g = lane >> 4, lm = lane & 15;
    const int mbase = mtile * 128 + w * 32;

    f32x4 acc[2][4] = {};
    for (int rr = 0; rr < 2; ++rr) {
        const int br = b * 10 + rg * 2 + rr;
        const float*  a0 = adj + (((size_t)br * 1024 + mbase + lm) << 10) + g * 8;
        const __bf16* y0 = yt  + (((size_t)br * 64 + lm) << 10) + g * 8;
        for (int n0 = 0; n0 < 1024; n0 += 32) {
            const f32x8 v0 = *(const f32x8*)(a0 + n0);
            const f32x8 v1 = *(const f32x8*)(a0 + (16 << 10) + n0);
            bf16x8 av0, av1;
#pragma unroll
            for (int j = 0; j < 8; ++j) { av0[j] = (__bf16)v0[j]; av1[j] = (__bf16)v1[j]; }
#pragma unroll
            for (int hf = 0; hf < 4; ++hf) {
                const bf16x8 bv = *(const bf16x8*)(y0 + hf * 16384 + n0);
                acc[0][hf] = __builtin_amdgcn_mfma_f32_16x16x32_bf16(av0, bv, acc[0][hf], 0, 0, 0);
                acc[1][hf] = __builtin_amdgcn_mfma_f32_16x16x32_bf16(av1, bv, acc[1][hf], 0, 0, 0);
            }
        }
    }
    float* pb = partial + (((size_t)rg * 16 + b) << 16) + (size_t)mbase * 64;
#pragma unroll
    for (int mf = 0; mf < 2; ++mf)
#pragma unroll
        for (int hf = 0; hf < 4; ++hf)
#pragma unroll
            for (int reg = 0; reg < 4; ++reg) {
                const int m = mf * 16 + g * 4 + reg;
                const int h = hf * 16 + lm;
                pb[((size_t)m << 6) + h] = acc[mf][hf][reg];
            }
}

// ---------------- epilogue: sum 5 partial slices + bias + relu ----------------
__global__ __launch_bounds__(256)
void rgcn_epi(const float* __restrict__ partial, const float* __restrict__ bias,
              float* __restrict__ dst) {
    const size_t i = (size_t)blockIdx.x * 256 + threadIdx.x;  // f32x4 index, 262144 total
    const size_t off = i * 4;                                  // float idx into [16][1024][64]
    f32x4 s = {};
#pragma unroll
    for (int p = 0; p < 5; ++p)
        s += *(const f32x4*)(partial + (size_t)p * 1048576 + off);
    const f32x4 bv = *(const f32x4*)(bias + (int)(off & 63));
#pragma unroll
    for (int j = 0; j < 4; ++j) s[j] = fmaxf(s[j] + bv[j], 0.f);
    *(f32x4*)(dst + off) = s;
}

extern "C" void kernel_launch(void* const* d_in, const int* in_sizes, int n_in,
                              void* d_out, int out_size, void* d_ws, size_t ws_size,
                              hipStream_t stream) {
    const float* x   = (const float*)d_in[0];   // [16,1024,64]
    const float* rel = (const float*)d_in[1];   // [16,10,32]
    const float* adj = (const float*)d_in[2];   // [16,10,1024,1024]
    const float* W0  = (const float*)d_in[3];   // [64,960]
    const float* b0  = (const float*)d_in[4];   // [64]
    const float* W1  = (const float*)d_in[5];
    const float* b1  = (const float*)d_in[6];
    float* out = (float*)d_out;                 // [16,1024,64]

    char* ws = (char*)d_ws;
    __bf16* Yt   = (__bf16*)ws;                 // 20,971,520 B (160 x 64 x 1024 bf16)
    float*  x2   = (float*)(ws + 20971520);     //  4,194,304 B
    float*  part = (float*)(ws + 25165824);     // 20,971,520 B (5 x 16 x 65536 f32)

    // layer 1: slow fused main (128 blocks) -> x2. Purpose: counters in top-5.
    rgcn_prep<<<dim3(4, 10, 16), 256, 0, stream>>>(x, rel, W0, Yt);
    rgcn_mainF<<<dim3(8, 1, 16), 256, 0, stream>>>(adj, Yt, b0, x2);

    // layer 2: fast path (r1-validated)
    rgcn_prep<<<dim3(4, 10, 16), 256, 0, stream>>>(x2, rel, W1, Yt);
    if (ws_size >= 46137344u) {
        rgcn_main<<<dim3(8, 5, 16), 256, 0, stream>>>(adj, Yt, part);
        rgcn_epi<<<1024, 256, 0, stream>>>(part, b1, out);
    } else {
        rgcn_mainF<<<dim3(8, 1, 16), 256, 0, stream>>>(adj, Yt, b1, out);
    }
}

// Round 11
// 658.070 us; speedup vs baseline: 1.2559x; 1.2559x over previous
//
#include <hip/hip_runtime.h>
#include <hip/hip_bf16.h>

// B=16, N=1024, R=10, De=64, Dr=32, H=64, cat_in=960
// out[b,m,h] = relu( bias[h] + sum_r sum_n adj[b,r,m,n] * Yt[br,h,n] )
// Yt[br,h,n] = sum_d x[b,n,d]*W[h, r*96+d] + c[br,h]
// c[br,h]    = sum_d rel[br,d]*W[h, r*96+64+d]
//
// r10 counters: mains were latency-starved (Occupancy 6%, VALUBusy 1.3%).
// Fix: K-split x4 -> 2560 blocks, launch_bounds(256,8) -> 32 waves/CU.

typedef __bf16 bf16x8 __attribute__((ext_vector_type(8)));
typedef float  f32x4  __attribute__((ext_vector_type(4)));
typedef float  f32x8  __attribute__((ext_vector_type(8)));

// ---------------- prep kernel: c (fused) + Yt[br,h,n] (bf16, linear) ----------------
__global__ __launch_bounds__(256)
void rgcn_prep(const float* __restrict__ x, const float* __restrict__ rel,
               const float* __restrict__ W, __bf16* __restrict__ yt) {
    const int r = blockIdx.y, b = blockIdx.z;
    const int br = b * 10 + r;

    __shared__ float csh[64];
    if (threadIdx.x < 64) {
        const int h = threadIdx.x;
        const float* rp = rel + (size_t)br * 32;
        const float* wp = W + (size_t)h * 960 + r * 96 + 64;
        float a = 0.f;
#pragma unroll
        for (int d = 0; d < 32; ++d) a += rp[d] * wp[d];
        csh[h] = a;
    }
    __syncthreads();

    const int n = blockIdx.x * 256 + threadIdx.x;   // 0..1023
    float xr[64];
    const float* xp = x + ((size_t)b * 1024 + n) * 64;
#pragma unroll
    for (int j = 0; j < 16; ++j) {
        const float4 v = *(const float4*)(xp + j * 4);
        xr[j * 4 + 0] = v.x; xr[j * 4 + 1] = v.y;
        xr[j * 4 + 2] = v.z; xr[j * 4 + 3] = v.w;
    }

    const float* wbase = W + r * 96;                 // W[h*960 + r*96 + d]
    __bf16* yb = yt + ((size_t)br << 16) + n;        // Yt[br][h][n], linear
    for (int h = 0; h < 64; ++h) {                   // h,d wave-uniform -> W scalar loads
        float acc = csh[h];
        const float* wr = wbase + (size_t)h * 960;
#pragma unroll
        for (int d = 0; d < 64; ++d) acc += xr[d] * wr[d];
        yb[(size_t)h << 10] = (__bf16)acc;
    }
}

// ---------------- main: K-split x4, full occupancy ----------------
// grid (8 mtile, 20 = rg*4+ks, 16 b), 256 thr = 4 waves, 48 VGPR < 64 cap
// -> 8 blocks/CU resident (32 waves/CU). Block: relations {rg*2, rg*2+1},
// k in [ks*256, ks*256+256). Partial slice p = rg*4+ks (20 slices).
// A-frag: adj row (lane&15 [+16]), k=(lane>>4)*8+j; B-frag same k-map (perm cancels).
// C/D: col=lane&15 (h), row=(lane>>4)*4+reg (m) — validated r1-r10.
__global__ __launch_bounds__(256, 8)
void rgcn_main(const float* __restrict__ adj, const __bf16* __restrict__ yt,
               float* __restrict__ partial) {
    const int mtile = blockIdx.x;
    const int rg = blockIdx.y >> 2, ks = blockIdx.y & 3;
    const int b = blockIdx.z;
    const int w = threadIdx.x >> 6, lane = threadIdx.x & 63;
    const int g = lane >> 4, lm = lane & 15;
    const int mbase = mtile * 128 + w * 32;
    const int n0lo = ks * 256, n0hi = n0lo + 256;

    f32x4 acc[2][4] = {};
    for (int rr = 0; rr < 2; ++rr) {
        const int br = b * 10 + rg * 2 + rr;
        const float*  a0 = adj + (((size_t)br * 1024 + mbase + lm) << 10) + g * 8;
        const __bf16* y0 = yt  + (((size_t)br * 64 + lm) << 10) + g * 8;
        for (int n0 = n0lo; n0 < n0hi; n0 += 32) {
            const f32x8 v0 = *(const f32x8*)(a0 + n0);
            const f32x8 v1 = *(const f32x8*)(a0 + (16 << 10) + n0);
            bf16x8 av0, av1;
#pragma unroll
            for (int j = 0; j < 8; ++j) { av0[j] = (__bf16)v0[j]; av1[j] = (__bf16)v1[j]; }
#pragma unroll
            for (int hf = 0; hf < 4; ++hf) {
                const bf16x8 bv = *(const bf16x8*)(y0 + hf * 16384 + n0);
                acc[0][hf] = __builtin_amdgcn_mfma_f32_16x16x32_bf16(av0, bv, acc[0][hf], 0, 0, 0);
                acc[1][hf] = __builtin_amdgcn_mfma_f32_16x16x32_bf16(av1, bv, acc[1][hf], 0, 0, 0);
            }
        }
    }
    float* pb = partial + (((size_t)blockIdx.y * 16 + b) << 16) + (size_t)mbase * 64;
#pragma unroll
    for (int mf = 0; mf < 2; ++mf)
#pragma unroll
        for (int hf = 0; hf < 4; ++hf)
#pragma unroll
            for (int reg = 0; reg < 4; ++reg) {
                const int m = mf * 16 + g * 4 + reg;
                const int h = hf * 16 + lm;
                pb[((size_t)m << 6) + h] = acc[mf][hf][reg];
            }
}

// ---------------- epilogue: sum 20 partial slices + bias + relu ----------------
__global__ __launch_bounds__(256)
void rgcn_epi(const float* __restrict__ partial, const float* __restrict__ bias,
              float* __restrict__ dst) {
    const size_t i = (size_t)blockIdx.x * 256 + threadIdx.x;  // f32x4 index, 262144 total
    const size_t off = i * 4;                                  // float idx into [16][1024][64]
    const size_t b = off >> 16;
    const size_t inner = off & 65535;
    f32x4 s = {};
#pragma unroll
    for (int p = 0; p < 20; ++p)
        s += *(const f32x4*)(partial + (((size_t)(p * 16) + b) << 16) + inner);
    const f32x4 bv = *(const f32x4*)(bias + (int)(off & 63));
#pragma unroll
    for (int j = 0; j < 4; ++j) s[j] = fmaxf(s[j] + bv[j], 0.f);
    *(f32x4*)(dst + off) = s;
}

// ---------------- fallback main (small ws): fp32, all 10 r, fused epilogue ----------------
__global__ __launch_bounds__(256, 2)
void rgcn_mainF(const float* __restrict__ adj, const __bf16* __restrict__ yt,
                const float* __restrict__ bias, float* __restrict__ dst) {
    const int mtile = blockIdx.x, b = blockIdx.z;
    const int w = threadIdx.x >> 6, lane = threadIdx.x & 63;
    const int g = lane >> 4, lm = lane & 15;
    const int mbase = mtile * 128 + w * 32;

    f32x4 acc[2][4] = {};
    for (int r = 0; r < 10; ++r) {
        const int br = b * 10 + r;
        const float*  a0 = adj + (((size_t)br * 1024 + mbase + lm) << 10) + g * 8;
        const __bf16* y0 = yt  + (((size_t)br * 64 + lm) << 10) + g * 8;
        for (int n0 = 0; n0 < 1024; n0 += 32) {
            const f32x8 v0 = *(const f32x8*)(a0 + n0);
            const f32x8 v1 = *(const f32x8*)(a0 + (16 << 10) + n0);
            bf16x8 av0, av1;
#pragma unroll
            for (int j = 0; j < 8; ++j) { av0[j] = (__bf16)v0[j]; av1[j] = (__bf16)v1[j]; }
#pragma unroll
            for (int hf = 0; hf < 4; ++hf) {
                const bf16x8 bv = *(const bf16x8*)(y0 + hf * 16384 + n0);
                acc[0][hf] = __builtin_amdgcn_mfma_f32_16x16x32_bf16(av0, bv, acc[0][hf], 0, 0, 0);
                acc[1][hf] = __builtin_amdgcn_mfma_f32_16x16x32_bf16(av1, bv, acc[1][hf], 0, 0, 0);
            }
        }
    }
    float bvals[4];
#pragma unroll
    for (int hf = 0; hf < 4; ++hf) bvals[hf] = bias[hf * 16 + lm];
    float* db = dst + ((size_t)(b * 1024 + mbase)) * 64;
#pragma unroll
    for (int mf = 0; mf < 2; ++mf)
#pragma unroll
        for (int hf = 0; hf < 4; ++hf)
#pragma unroll
            for (int reg = 0; reg < 4; ++reg) {
                const int m = mf * 16 + g * 4 + reg;
                const int h = hf * 16 + lm;
                db[((size_t)m << 6) + h] = fmaxf(acc[mf][hf][reg] + bvals[hf], 0.f);
            }
}

extern "C" void kernel_launch(void* const* d_in, const int* in_sizes, int n_in,
                              void* d_out, int out_size, void* d_ws, size_t ws_size,
                              hipStream_t stream) {
    const float* x   = (const float*)d_in[0];   // [16,1024,64]
    const float* rel = (const float*)d_in[1];   // [16,10,32]
    const float* adj = (const float*)d_in[2];   // [16,10,1024,1024]
    const float* W0  = (const float*)d_in[3];   // [64,960]
    const float* b0  = (const float*)d_in[4];   // [64]
    const float* W1  = (const float*)d_in[5];
    const float* b1  = (const float*)d_in[6];
    float* out = (float*)d_out;                 // [16,1024,64]

    char* ws = (char*)d_ws;
    __bf16* Yt   = (__bf16*)ws;                 // 20,971,520 B (160 x 64 x 1024 bf16)
    float*  x2   = (float*)(ws + 20971520);     //  4,194,304 B
    float*  part = (float*)(ws + 25165824);     // 83,886,080 B (20 x 16 x 65536 f32)
    const bool big = ws_size >= 109051904u;

    for (int layer = 0; layer < 2; ++layer) {
        const float* xin  = layer ? x2 : x;
        const float* W    = layer ? W1 : W0;
        const float* bias = layer ? b1 : b0;
        float* dst        = layer ? out : x2;

        rgcn_prep<<<dim3(4, 10, 16), 256, 0, stream>>>(xin, rel, W, Yt);
        if (big) {
            rgcn_main<<<dim3(8, 20, 16), 256, 0, stream>>>(adj, Yt, part);
            rgcn_epi<<<1024, 256, 0, stream>>>(part, bias, dst);
        } else {
            rgcn_mainF<<<dim3(8, 1, 16), 256, 0, stream>>>(adj, Yt, bias, dst);
        }
    }
}